// Round 5
// baseline (1352.284 us; speedup 1.0000x reference)
//
#include <hip/hip_runtime.h>
#include <math.h>

#define T_TOK 2048
#define NE 64
#define KTOP 8
#define CAPC 512
#define DIN 768
#define HD 2048
#define BTD 256
#define OD 768

typedef short bf16x8 __attribute__((ext_vector_type(8)));
typedef float f32x4 __attribute__((ext_vector_type(4)));

__device__ __forceinline__ unsigned short f2bf(float f) {
  unsigned u = __float_as_uint(f);
  u += 0x7FFF + ((u >> 16) & 1);   // round-to-nearest-even
  return (unsigned short)(u >> 16);
}
__device__ __forceinline__ unsigned cvt2(float a, float b) {
  unsigned r;
  asm("v_cvt_pk_bf16_f32 %0, %1, %2" : "=v"(r) : "v"(a), "v"(b));
  return r;   // lo = bf16(a), hi = bf16(b)
}
__device__ __forceinline__ float gelu_exact(float v) {
  return 0.5f * v * (1.0f + erff(v * 0.7071067811865476f));
}
__device__ __forceinline__ void glds16(unsigned short* lds, const unsigned short* g) {
  __builtin_amdgcn_global_load_lds(
      (const __attribute__((address_space(1))) void*)g,
      (__attribute__((address_space(3))) void*)lds, 16, 0, 0);
}

// ---------------- x fp32 -> bf16 ---------------------------------------------------
__global__ __launch_bounds__(256) void cvt_x(const float* __restrict__ x,
                                             unsigned short* __restrict__ xb) {
  int i = blockIdx.x * 256 + threadIdx.x;
  float4 v = ((const float4*)x)[i];
  ushort4 o;
  o.x = f2bf(v.x); o.y = f2bf(v.y); o.z = f2bf(v.z); o.w = f2bf(v.w);
  ((ushort4*)xb)[i] = o;
}

// ---------------- router: fp32 logits, noisy top-8, softmax, gate/slot matrices ----
__global__ __launch_bounds__(256) void router_kernel(
    const float* __restrict__ x, const float* __restrict__ noise,
    const float* __restrict__ Wr, const float* __restrict__ br,
    const float* __restrict__ Wn, const float* __restrict__ bn,
    float* __restrict__ gate, int* __restrict__ slotm)
{
  __shared__ float xs[8][DIN];
  __shared__ float wrs[64][NE];
  __shared__ float wns[64][NE];
  const int tid = threadIdx.x;
  const int t0 = blockIdx.x * 8;
  for (int i = tid; i < 8 * (DIN / 4); i += 256) {
    int tt = i / (DIN / 4), c = i % (DIN / 4);
    ((float4*)xs[tt])[c] = ((const float4*)(x + (size_t)(t0 + tt) * DIN))[c];
  }
  const int lane = tid & 63;
  const int wv = tid >> 6;
  const int e = lane;
  const int ta = 2 * wv, tb = ta + 1;
  float ar0 = br[e], ar1 = ar0, an0 = bn[e], an1 = an0;
  for (int d0 = 0; d0 < DIN; d0 += 64) {
    __syncthreads();
    for (int i = tid; i < 64 * NE / 4; i += 256) {
      int dd = i >> 4, c4 = (i & 15) * 4;
      *(float4*)&wrs[dd][c4] = *(const float4*)&Wr[(size_t)(d0 + dd) * NE + c4];
      *(float4*)&wns[dd][c4] = *(const float4*)&Wn[(size_t)(d0 + dd) * NE + c4];
    }
    __syncthreads();
    #pragma unroll 8
    for (int dd = 0; dd < 64; dd++) {
      float wr = wrs[dd][e], wn = wns[dd][e];
      float xa = xs[ta][d0 + dd], xb = xs[tb][d0 + dd];
      ar0 = fmaf(xa, wr, ar0); ar1 = fmaf(xb, wr, ar1);
      an0 = fmaf(xa, wn, an0); an1 = fmaf(xb, wn, an1);
    }
  }
  #pragma unroll
  for (int s = 0; s < 2; s++) {
    int t = t0 + ta + s;
    float lr = s ? ar1 : ar0;
    float lnv = s ? an1 : an0;
    float sp = fmaxf(lnv, 0.f) + log1pf(expf(-fabsf(lnv)));   // softplus, overflow-safe
    float v = lr + noise[(size_t)t * NE + e] * sp;
    float cur = v;
    float topv[KTOP]; int topi[KTOP];
    #pragma unroll
    for (int j = 0; j < KTOP; j++) {
      float bv = cur; int bi = e;
      #pragma unroll
      for (int off = 32; off > 0; off >>= 1) {
        float ov = __shfl_xor(bv, off);
        int   oi = __shfl_xor(bi, off);
        if (ov > bv || (ov == bv && oi < bi)) { bv = ov; bi = oi; }
      }
      topv[j] = bv; topi[j] = bi;
      if (e == bi) cur = -INFINITY;
    }
    float mx = topv[0], se = 0.f, pv[KTOP];
    #pragma unroll
    for (int j = 0; j < KTOP; j++) { pv[j] = expf(topv[j] - mx); se += pv[j]; }
    float inv = 1.f / se;
    float g = 0.f; int sl = -1;
    #pragma unroll
    for (int j = 0; j < KTOP; j++) if (topi[j] == e) { g = pv[j] * inv; sl = j; }
    gate[(size_t)t * NE + e] = (sl >= 0) ? g : 0.f;
    slotm[(size_t)t * NE + e] = sl;
  }
}

// ---------------- dispatch: stable per-expert compaction (== stable argsort) -------
__global__ __launch_bounds__(256) void dispatch_kernel(
    const float* __restrict__ gate, const int* __restrict__ slotm,
    int* __restrict__ tok_idx, float* __restrict__ tok_g,
    int* __restrict__ tok_slot, int* __restrict__ counts)
{
  const int e = blockIdx.x;
  const int tid = threadIdx.x;
  __shared__ int wave_off[4];
  int base = 0;
  for (int t0 = 0; t0 < T_TOK; t0 += 256) {
    int t = t0 + tid;
    float g = gate[(size_t)t * NE + e];
    bool p = g > 0.f;
    unsigned long long m = __ballot(p);
    int wv = tid >> 6, lane = tid & 63;
    int pre = __popcll(m & ((1ull << lane) - 1ull));
    if (lane == 0) wave_off[wv] = __popcll(m);
    __syncthreads();
    int off = 0;
    for (int w = 0; w < wv; w++) off += wave_off[w];
    int tot = wave_off[0] + wave_off[1] + wave_off[2] + wave_off[3];
    if (p) {
      int pos = base + off + pre;
      if (pos < CAPC) {
        tok_idx[(size_t)e * CAPC + pos] = t;
        tok_g[(size_t)e * CAPC + pos] = g;
        tok_slot[(size_t)e * CAPC + pos] = slotm[(size_t)t * NE + e];
      }
    }
    base += tot;
    __syncthreads();
  }
  if (tid == 0) counts[e] = min(base, CAPC);
}

// ============== BIG expert GEMM: 256x128x32, 512 thr, role-split staging ===========
// Waves 0-3: stage fp32 B -> regs -> cvt -> LDS [128][40] (conflict-free reads).
// Waves 4-7: stage bf16 A via global_load_lds, chunk-permuted source addresses so the
//            linear [256][32] layout gives conflict-free swizzled fragment reads.
// All 8 waves compute a 64x64 output sub-tile. Depth-3 counted-vmcnt pipeline,
// 4 LDS buffers; B panels are fetched once per expert (BM=256 >= typical cnt).
template<int KD, int NDT, bool AGATHER, int EPI>
__global__ __launch_bounds__(512, 1) void moe_gemm_big(
    const unsigned short* __restrict__ Abf, const float* __restrict__ Bw,
    const float* __restrict__ bias, void* __restrict__ Outp,
    const int* __restrict__ tok_idx, const float* __restrict__ tok_g,
    const int* __restrict__ tok_slot, const int* __restrict__ counts)
{
  constexpr int NK = KD / 32;
  static_assert(NK % 4 == 0 && NK >= 8, "NK must be multiple of 4");
  const int e = blockIdx.z;
  const int cnt = counts[e];
  const int m0 = blockIdx.y * 256;
  if (m0 >= cnt) return;
  const int n0 = blockIdx.x * 128;
  const int tid = threadIdx.x;
  const int lane = tid & 63, wave = tid >> 6;

  __shared__ unsigned short AL[4][256][32];   // 64 KB, linear (gload_lds dest)
  __shared__ unsigned short BL[4][128][40];   // 40 KB, 80B rows
  __shared__ int   s_tok[256];
  __shared__ float s_g[256];
  __shared__ int   s_slot[256];

  if (EPI == 2 && tid < 256) {
    int gr = m0 + tid;
    if (gr < cnt) {
      s_tok[tid]  = tok_idx[(size_t)e * CAPC + gr];
      s_g[tid]    = tok_g[(size_t)e * CAPC + gr];
      s_slot[tid] = tok_slot[(size_t)e * CAPC + gr];
    }
  }

  const bool isB = wave < 4;
  const int  w4  = wave & 3;

  // ---- B staging (waves 0-3): lane covers cols n0+2*lane..+1, k rows 8*w4..+7 ----
  const float* bp = Bw + (size_t)e * KD * NDT + (size_t)(8 * w4) * NDT + n0 + 2 * lane;
  float2 breg[4][8];

  // ---- A staging (waves 4-7): 4 glds16/thread; idx = w4*256 + q*64 + lane ----
  //      row r = idx>>2, slot s = lane&3 holds global chunk ((lane&3)-(r>>1))&3
  size_t a_off[4];
  if (!isB) {
    #pragma unroll
    for (int q = 0; q < 4; q++) {
      int r  = w4 * 64 + q * 16 + (lane >> 2);
      int cq = ((lane & 3) - (r >> 1)) & 3;
      size_t rowb;
      if (AGATHER) {
        int gr = m0 + r;
        int tk = (gr < cnt) ? tok_idx[(size_t)e * CAPC + gr] : 0;
        rowb = (size_t)tk * KD;
      } else {
        rowb = ((size_t)e * CAPC + m0 + r) * KD;
      }
      a_off[q] = rowb + 8 * cq;
    }
  }

  auto stageA = [&](int t, int s) {
    #pragma unroll
    for (int q = 0; q < 4; q++)
      glds16(&AL[s][0][0] + w4 * 2048 + q * 512, Abf + a_off[q] + (size_t)t * 32);
  };
  auto loadB = [&](int t, int p) {
    const float* pb = bp + (size_t)t * 32 * NDT;
    #pragma unroll
    for (int j = 0; j < 8; j++) breg[p][j] = *(const float2*)(pb + (size_t)j * NDT);
  };
  auto writeB = [&](int s, int p) {
    uint4 rx, ry;
    rx.x = cvt2(breg[p][0].x, breg[p][1].x); rx.y = cvt2(breg[p][2].x, breg[p][3].x);
    rx.z = cvt2(breg[p][4].x, breg[p][5].x); rx.w = cvt2(breg[p][6].x, breg[p][7].x);
    ry.x = cvt2(breg[p][0].y, breg[p][1].y); ry.y = cvt2(breg[p][2].y, breg[p][3].y);
    ry.z = cvt2(breg[p][4].y, breg[p][5].y); ry.w = cvt2(breg[p][6].y, breg[p][7].y);
    *(uint4*)&BL[s][2 * lane][8 * w4]     = rx;
    *(uint4*)&BL[s][2 * lane + 1][8 * w4] = ry;
  };

  // ---- MFMA setup: wave grid 4m x 2n, per-wave 64x64 ----
  const int wm = (wave >> 1) * 64;
  const int wn = (wave & 1) * 64;
  const int li = lane & 15, lg = lane >> 4;
  const int kxa = 8 * ((lg + ((li >> 1) & 3)) & 3);   // A swizzled chunk col

  f32x4 acc[4][4];
  #pragma unroll
  for (int i = 0; i < 4; i++)
    #pragma unroll
    for (int j = 0; j < 4; j++) acc[i][j] = (f32x4){0.f, 0.f, 0.f, 0.f};

  auto step = [&](int s) {
    bf16x8 afr[4], bfr[4];
    #pragma unroll
    for (int mi = 0; mi < 4; mi++)
      afr[mi] = *(const bf16x8*)&AL[s][wm + mi * 16 + li][kxa];
    #pragma unroll
    for (int ni = 0; ni < 4; ni++)
      bfr[ni] = *(const bf16x8*)&BL[s][wn + ni * 16 + li][lg * 8];
    __builtin_amdgcn_s_setprio(1);
    #pragma unroll
    for (int mi = 0; mi < 4; mi++)
      #pragma unroll
      for (int ni = 0; ni < 4; ni++)
        acc[mi][ni] = __builtin_amdgcn_mfma_f32_16x16x32_bf16(afr[mi], bfr[ni], acc[mi][ni], 0, 0, 0);
    __builtin_amdgcn_s_setprio(0);
  };

  // ---- prologue: tiles 0..2 in flight; B tile 0 to LDS ----
  if (isB) {
    loadB(0, 0); loadB(1, 1); loadB(2, 2);                 // 24 vm out (+pre-loop)
    asm volatile("s_waitcnt vmcnt(16)" ::: "memory");      // retire loadB(0)
    writeB(0, 0);
    asm volatile("s_waitcnt lgkmcnt(0)" ::: "memory");
  } else {
    stageA(0, 0); stageA(1, 1); stageA(2, 2);              // 12 vm out
    asm volatile("s_waitcnt vmcnt(8)" ::: "memory");       // stageA(0) landed
  }
  __builtin_amdgcn_s_barrier();

  // steady state, sub-iter j (p=j&3):
  //   stage tile j+3 into buf (p+3)&3; compute tile j from buf p;
  //   B-waves: vmcnt(16) retires loadB(j+1) -> writeB(j+1); lgkm0
  //   A-waves: vmcnt(8)  retires stageA(j+1) LDS writes
  //   barrier -> tile j+1 published to all waves
  #define SUBITER(p)                                                        \
    do {                                                                    \
      const int jj = jb + (p);                                              \
      if (isB) loadB(min(jj + 3, NK - 1), ((p) + 3) & 3);                   \
      else     stageA(min(jj + 3, NK - 1), ((p) + 3) & 3);                  \
      step(p);                                                              \
      if (isB) {                                                            \
        asm volatile("s_waitcnt vmcnt(16)" ::: "memory");                   \
        writeB(((p) + 1) & 3, ((p) + 1) & 3);                               \
        asm volatile("s_waitcnt lgkmcnt(0)" ::: "memory");                  \
      } else {                                                              \
        asm volatile("s_waitcnt vmcnt(8)" ::: "memory");                    \
      }                                                                     \
      __builtin_amdgcn_s_barrier();                                         \
    } while (0)

  for (int jb = 0; jb < NK; jb += 4) {
    SUBITER(0); SUBITER(1); SUBITER(2); SUBITER(3);
  }
  #undef SUBITER
  asm volatile("s_waitcnt vmcnt(0)" ::: "memory");   // drain before WG exit

  // ---- epilogue ----
  const float* bpb = bias + (size_t)e * NDT;
  #pragma unroll
  for (int mi = 0; mi < 4; mi++) {
    #pragma unroll
    for (int ni = 0; ni < 4; ni++) {
      const int ncol = n0 + wn + ni * 16 + li;
      const float bb = bpb[ncol];
      #pragma unroll
      for (int q = 0; q < 4; q++) {
        const int r = wm + mi * 16 + lg * 4 + q;
        const int gr = m0 + r;
        if (gr < cnt) {
          float v = acc[mi][ni][q] + bb;
          if (EPI == 0) {
            v = gelu_exact(v);
            ((unsigned short*)Outp)[((size_t)e * CAPC + gr) * NDT + ncol] = f2bf(v);
          } else if (EPI == 1) {
            ((unsigned short*)Outp)[((size_t)e * CAPC + gr) * NDT + ncol] = f2bf(v);
          } else {
            ((float*)Outp)[((size_t)s_tok[r] * KTOP + s_slot[r]) * OD + ncol] = v * s_g[r];
          }
        }
      }
    }
  }
}

// ---------------- 128x128x32 expert GEMM (round-4, verified) for GEMM3/4 -----------
template<int KD, int ND, bool AGATHER, int EPI>
__global__ __launch_bounds__(256, 2) void moe_gemm(
    const unsigned short* __restrict__ Abf, const float* __restrict__ Bw,
    const float* __restrict__ bias, void* __restrict__ Outp,
    const int* __restrict__ tok_idx, const float* __restrict__ tok_g,
    const int* __restrict__ tok_slot, const int* __restrict__ counts)
{
  constexpr int NK = KD / 32;
  static_assert(NK % 4 == 0 && NK >= 8, "NK must be multiple of 4");
  const int e = blockIdx.z;
  const int cnt = counts[e];
  const int m0 = blockIdx.y * 128;
  if (m0 >= cnt) return;
  const int n0 = blockIdx.x * 128;
  const int tid = threadIdx.x;

  __shared__ unsigned short AL[4][128][32];
  __shared__ unsigned short BL[4][128][40];
  __shared__ int   s_tok[128];
  __shared__ float s_g[128];
  __shared__ int   s_slot[128];

  if (EPI == 2 && tid < 128) {
    int gr = m0 + tid;
    if (gr < cnt) {
      s_tok[tid]  = tok_idx[(size_t)e * CAPC + gr];
      s_g[tid]    = tok_g[(size_t)e * CAPC + gr];
      s_slot[tid] = tok_slot[(size_t)e * CAPC + gr];
    }
  }

  const int ar0 = tid >> 2;
  const int ac  = 8 * (((tid & 3) - (tid >> 3)) & 3);
  size_t arow0, arow1;
  if (AGATHER) {
    int g0 = m0 + ar0, g1 = m0 + 64 + ar0;
    int t0i = (g0 < cnt) ? tok_idx[(size_t)e * CAPC + g0] : 0;
    int t1i = (g1 < cnt) ? tok_idx[(size_t)e * CAPC + g1] : 0;
    arow0 = (size_t)t0i * KD; arow1 = (size_t)t1i * KD;
  } else {
    arow0 = ((size_t)e * CAPC + m0 + ar0) * KD;
    arow1 = arow0 + (size_t)64 * KD;
  }
  const unsigned short* ap0 = Abf + arow0 + ac;
  const unsigned short* ap1 = Abf + arow1 + ac;
  const int awb = (tid & 192) * 8;

  const int l = tid & 63, w = tid >> 6;
  const float* bp = Bw + (size_t)e * KD * ND + (size_t)(8 * w) * ND + n0 + 2 * l;

  float2 breg[4][8];

  auto stageA = [&](int t, int s) {
    glds16(&AL[s][0][0] + awb,        ap0 + t * 32);
    glds16(&AL[s][0][0] + 2048 + awb, ap1 + t * 32);
  };
  auto loadB = [&](int t, int p) {
    const float* pb = bp + (size_t)t * 32 * ND;
    #pragma unroll
    for (int j = 0; j < 8; j++) breg[p][j] = *(const float2*)(pb + (size_t)j * ND);
  };
  auto writeB = [&](int s, int p) {
    uint4 rx, ry;
    rx.x = cvt2(breg[p][0].x, breg[p][1].x); rx.y = cvt2(breg[p][2].x, breg[p][3].x);
    rx.z = cvt2(breg[p][4].x, breg[p][5].x); rx.w = cvt2(breg[p][6].x, breg[p][7].x);
    ry.x = cvt2(breg[p][0].y, breg[p][1].y); ry.y = cvt2(breg[p][2].y, breg[p][3].y);
    ry.z = cvt2(breg[p][4].y, breg[p][5].y); ry.w = cvt2(breg[p][6].y, breg[p][7].y);
    *(uint4*)&BL[s][2 * l][8 * w]     = rx;
    *(uint4*)&BL[s][2 * l + 1][8 * w] = ry;
  };

  const int lane = tid & 63, wv = tid >> 6;
  const int wm = (wv >> 1) * 64, wn = (wv & 1) * 64;
  const int li = lane & 15, lg = lane >> 4;
  const int kxa = 8 * ((lg + ((li >> 1) & 3)) & 3);

  f32x4 acc[4][4];
  #pragma unroll
  for (int i = 0; i < 4; i++)
    #pragma unroll
    for (int j = 0; j < 4; j++) acc[i][j] = (f32x4){0.f, 0.f, 0.f, 0.f};

  auto step = [&](int s) {
    bf16x8 afr[4], bfr[4];
    #pragma unroll
    for (int mi = 0; mi < 4; mi++)
      afr[mi] = *(const bf16x8*)&AL[s][wm + mi * 16 + li][kxa];
    #pragma unroll
    for (int ni = 0; ni < 4; ni++)
      bfr[ni] = *(const bf16x8*)&BL[s][wn + ni * 16 + li][lg * 8];
    __builtin_amdgcn_s_setprio(1);
    #pragma unroll
    for (int mi = 0; mi < 4; mi++)
      #pragma unroll
      for (int ni = 0; ni < 4; ni++)
        acc[mi][ni] = __builtin_amdgcn_mfma_f32_16x16x32_bf16(afr[mi], bfr[ni], acc[mi][ni], 0, 0, 0);
    __builtin_amdgcn_s_setprio(0);
  };

  loadB(0, 0);
  stageA(0, 0); loadB(1, 1);
  stageA(1, 1); loadB(2, 2);
  stageA(2, 2); loadB(3, 3);
  asm volatile("s_waitcnt vmcnt(28)" ::: "memory");
  writeB(0, 0);
  asm volatile("s_waitcnt lgkmcnt(0)" ::: "memory");
  __builtin_amdgcn_s_barrier();

  #define SUBITER(p)                                                        \
    do {                                                                    \
      const int jj = jb + (p);                                              \
      stageA(min(jj + 3, NK - 1), ((p) + 3) & 3);                           \
      loadB(min(jj + 4, NK - 1), (p));                                      \
      step(p);                                                              \
      asm volatile("s_waitcnt vmcnt(28)" ::: "memory");                     \
      writeB(((p) + 1) & 3, ((p) + 1) & 3);                                 \
      asm volatile("s_waitcnt lgkmcnt(0)" ::: "memory");                    \
      __builtin_amdgcn_s_barrier();                                         \
    } while (0)

  for (int jb = 0; jb < NK; jb += 4) {
    SUBITER(0); SUBITER(1); SUBITER(2); SUBITER(3);
  }
  #undef SUBITER
  asm volatile("s_waitcnt vmcnt(0)" ::: "memory");

  const float* bpb = bias + (size_t)e * ND;
  #pragma unroll
  for (int mi = 0; mi < 4; mi++) {
    #pragma unroll
    for (int ni = 0; ni < 4; ni++) {
      const int ncol = n0 + wn + ni * 16 + li;
      const float bb = bpb[ncol];
      #pragma unroll
      for (int q = 0; q < 4; q++) {
        const int r = wm + mi * 16 + lg * 4 + q;
        const int gr = m0 + r;
        if (gr < cnt) {
          float v = acc[mi][ni][q] + bb;
          if (EPI == 0) {
            v = gelu_exact(v);
            ((unsigned short*)Outp)[((size_t)e * CAPC + gr) * ND + ncol] = f2bf(v);
          } else if (EPI == 1) {
            ((unsigned short*)Outp)[((size_t)e * CAPC + gr) * ND + ncol] = f2bf(v);
          } else {
            ((float*)Outp)[((size_t)s_tok[r] * KTOP + s_slot[r]) * OD + ncol] = v * s_g[r];
          }
        }
      }
    }
  }
}

// ---------------- combine 8 slots + LayerNorm -------------------------------------
__global__ __launch_bounds__(256) void combine_ln(
    const float* __restrict__ yd, const float* __restrict__ lw,
    const float* __restrict__ lb, float* __restrict__ out)
{
  const int t = blockIdx.x, tid = threadIdx.x;
  float v[3];
  #pragma unroll
  for (int i = 0; i < 3; i++) {
    const int c = tid + 256 * i;
    float s = 0.f;
    #pragma unroll
    for (int j = 0; j < KTOP; j++) s += yd[((size_t)t * KTOP + j) * OD + c];
    v[i] = s;
  }
  float s1 = v[0] + v[1] + v[2];
  float s2 = v[0] * v[0] + v[1] * v[1] + v[2] * v[2];
  #pragma unroll
  for (int off = 32; off > 0; off >>= 1) {
    s1 += __shfl_xor(s1, off);
    s2 += __shfl_xor(s2, off);
  }
  __shared__ float as1[4], as2[4];
  const int lane = tid & 63, wv = tid >> 6;
  if (lane == 0) { as1[wv] = s1; as2[wv] = s2; }
  __syncthreads();
  s1 = as1[0] + as1[1] + as1[2] + as1[3];
  s2 = as2[0] + as2[1] + as2[2] + as2[3];
  const float mu = s1 * (1.f / OD);
  const float var = s2 * (1.f / OD) - mu * mu;
  const float rstd = rsqrtf(var + 1e-5f);
  #pragma unroll
  for (int i = 0; i < 3; i++) {
    const int c = tid + 256 * i;
    out[(size_t)t * OD + c] = (v[i] - mu) * rstd * lw[c] + lb[c];
  }
}

extern "C" void kernel_launch(void* const* d_in, const int* in_sizes, int n_in,
                              void* d_out, int out_size, void* d_ws, size_t ws_size,
                              hipStream_t stream) {
  const float* x     = (const float*)d_in[0];
  const float* noise = (const float*)d_in[1];
  const float* Wr    = (const float*)d_in[2];
  const float* br    = (const float*)d_in[3];
  const float* Wn    = (const float*)d_in[4];
  const float* bn    = (const float*)d_in[5];
  const float* W1    = (const float*)d_in[6];
  const float* b1    = (const float*)d_in[7];
  const float* W2    = (const float*)d_in[8];
  const float* b2    = (const float*)d_in[9];
  const float* W3    = (const float*)d_in[10];
  const float* b3    = (const float*)d_in[11];
  const float* Wo    = (const float*)d_in[12];
  const float* bo    = (const float*)d_in[13];
  const float* lw    = (const float*)d_in[14];
  const float* lb    = (const float*)d_in[15];
  float* out = (float*)d_out;

  char* ws = (char*)d_ws;
  constexpr size_t OFF_GATE = 0;
  constexpr size_t OFF_SLOT = OFF_GATE + (size_t)T_TOK * NE * 4;
  constexpr size_t OFF_TIDX = OFF_SLOT + (size_t)T_TOK * NE * 4;
  constexpr size_t OFF_TG   = OFF_TIDX + (size_t)NE * CAPC * 4;
  constexpr size_t OFF_TSL  = OFF_TG + (size_t)NE * CAPC * 4;
  constexpr size_t OFF_CNT  = OFF_TSL + (size_t)NE * CAPC * 4;
  constexpr size_t OFF_YD   = ((OFF_CNT + NE * 4) + 255) & ~(size_t)255;
  constexpr size_t SZ_YD    = (size_t)T_TOK * KTOP * OD * 4;
  constexpr size_t OFF_H1   = OFF_YD + SZ_YD;
  constexpr size_t OFF_H2   = OFF_H1 + (size_t)NE * CAPC * HD * 2;
  constexpr size_t OFF_H3   = OFF_H2 + (size_t)NE * CAPC * HD * 2;
  constexpr size_t OFF_XBF  = OFF_H3 + (size_t)NE * CAPC * BTD * 2;

  float* gate = (float*)(ws + OFF_GATE);
  int*   slot = (int*)(ws + OFF_SLOT);
  int*   tidx = (int*)(ws + OFF_TIDX);
  float* tg   = (float*)(ws + OFF_TG);
  int*   tsl  = (int*)(ws + OFF_TSL);
  int*   cnts = (int*)(ws + OFF_CNT);
  float* yd   = (float*)(ws + OFF_YD);
  unsigned short* h1  = (unsigned short*)(ws + OFF_H1);
  unsigned short* h2  = (unsigned short*)(ws + OFF_H2);
  unsigned short* h3  = (unsigned short*)(ws + OFF_H3);
  unsigned short* xbf = (unsigned short*)(ws + OFF_XBF);

  hipMemsetAsync(yd, 0, SZ_YD, stream);
  cvt_x<<<T_TOK * DIN / 4 / 256, 256, 0, stream>>>(x, xbf);
  router_kernel<<<T_TOK / 8, 256, 0, stream>>>(x, noise, Wr, br, Wn, bn, gate, slot);
  dispatch_kernel<<<NE, 256, 0, stream>>>(gate, slot, tidx, tg, tsl, cnts);
  moe_gemm_big<DIN, HD, true, 0><<<dim3(HD / 128, CAPC / 256, NE), 512, 0, stream>>>(
      xbf, W1, b1, h1, tidx, tg, tsl, cnts);
  moe_gemm_big<HD, HD, false, 0><<<dim3(HD / 128, CAPC / 256, NE), 512, 0, stream>>>(
      h1, W2, b2, h2, tidx, tg, tsl, cnts);
  moe_gemm<HD, BTD, false, 1><<<dim3(BTD / 128, CAPC / 128, NE), 256, 0, stream>>>(
      h2, W3, b3, h3, tidx, tg, tsl, cnts);
  moe_gemm<BTD, OD, false, 2><<<dim3(OD / 128, CAPC / 128, NE), 256, 0, stream>>>(
      h3, Wo, bo, yd, tidx, tg, tsl, cnts);
  combine_ln<<<T_TOK, 256, 0, stream>>>(yd, lw, lb, out);
}

// Round 6
// 1332.451 us; speedup vs baseline: 1.0149x; 1.0149x over previous
//
#include <hip/hip_runtime.h>
#include <math.h>

#define T_TOK 2048
#define NE 64
#define KTOP 8
#define CAPC 512
#define DIN 768
#define HD 2048
#define BTD 256
#define OD 768

typedef short bf16x8 __attribute__((ext_vector_type(8)));
typedef float f32x4 __attribute__((ext_vector_type(4)));

__device__ __forceinline__ unsigned short f2bf(float f) {
  unsigned u = __float_as_uint(f);
  u += 0x7FFF + ((u >> 16) & 1);   // round-to-nearest-even
  return (unsigned short)(u >> 16);
}
__device__ __forceinline__ unsigned cvt2(float a, float b) {
  unsigned r;
  asm("v_cvt_pk_bf16_f32 %0, %1, %2" : "=v"(r) : "v"(a), "v"(b));
  return r;   // lo = bf16(a), hi = bf16(b)
}
__device__ __forceinline__ float gelu_exact(float v) {
  return 0.5f * v * (1.0f + erff(v * 0.7071067811865476f));
}
__device__ __forceinline__ void glds16(unsigned short* lds, const unsigned short* g) {
  __builtin_amdgcn_global_load_lds(
      (const __attribute__((address_space(1))) void*)g,
      (__attribute__((address_space(3))) void*)lds, 16, 0, 0);
}

// ---------------- x fp32 -> bf16 ---------------------------------------------------
__global__ __launch_bounds__(256) void cvt_x(const float* __restrict__ x,
                                             unsigned short* __restrict__ xb) {
  int i = blockIdx.x * 256 + threadIdx.x;
  float4 v = ((const float4*)x)[i];
  ushort4 o;
  o.x = f2bf(v.x); o.y = f2bf(v.y); o.z = f2bf(v.z); o.w = f2bf(v.w);
  ((ushort4*)xb)[i] = o;
}

// ---------------- weight retile: fp32 [K][N] -> bf16 GEMM-native 8KB tiles ----------
// Output tile (e,p,t): ushort[4096]; pos n'*32 + s*8 + j  holds  bf16 of
// W[e][32t + 8*((s-((n'>>1)&3))&3) + j][128p + n']  — i.e., exactly the LDS image
// moe_gemm_t's fragment reads expect (chunk-permute swizzle included).
template<int KD, int ND>
__global__ __launch_bounds__(256) void retile_w(const float* __restrict__ W,
                                                unsigned short* __restrict__ Bt) {
  constexpr int KT = KD / 32;
  constexpr int NP = ND / 128;
  constexpr int PH = ND / 256;
  const int t = blockIdx.x;
  const int e = blockIdx.y;
  const int tid = threadIdx.x;
  __shared__ float L[32][257];
  for (int np = 0; np < PH; np++) {
    #pragma unroll
    for (int j = 0; j < 8; j++) {
      int idx = j * 256 + tid;
      int row = idx >> 6, c4 = idx & 63;
      *(float4*)&L[row][4 * c4] =
          *(const float4*)&W[((size_t)e * KD + 32 * t + row) * ND + 256 * np + 4 * c4];
    }
    __syncthreads();
    #pragma unroll
    for (int q = 0; q < 4; q++) {
      int oid = q * 256 + tid;
      int nl = oid >> 2, s = oid & 3;
      int n = 256 * np + nl;
      int pp = n >> 7, nr = n & 127;
      int c = (s - ((nr >> 1) & 3)) & 3;
      union { bf16x8 v; unsigned u32[4]; } pk;
      #pragma unroll
      for (int h = 0; h < 4; h++)
        pk.u32[h] = cvt2(L[8 * c + 2 * h][nl], L[8 * c + 2 * h + 1][nl]);
      *(bf16x8*)&Bt[(((size_t)e * NP + pp) * KT + t) * 4096 + nr * 32 + s * 8] = pk.v;
    }
    __syncthreads();
  }
}

// ---------------- router: fp32 logits, noisy top-8, softmax, gate/slot matrices ----
__global__ __launch_bounds__(256) void router_kernel(
    const float* __restrict__ x, const float* __restrict__ noise,
    const float* __restrict__ Wr, const float* __restrict__ br,
    const float* __restrict__ Wn, const float* __restrict__ bn,
    float* __restrict__ gate, int* __restrict__ slotm)
{
  __shared__ float xs[8][DIN];
  __shared__ float wrs[64][NE];
  __shared__ float wns[64][NE];
  const int tid = threadIdx.x;
  const int t0 = blockIdx.x * 8;
  for (int i = tid; i < 8 * (DIN / 4); i += 256) {
    int tt = i / (DIN / 4), c = i % (DIN / 4);
    ((float4*)xs[tt])[c] = ((const float4*)(x + (size_t)(t0 + tt) * DIN))[c];
  }
  const int lane = tid & 63;
  const int wv = tid >> 6;
  const int e = lane;
  const int ta = 2 * wv, tb = ta + 1;
  float ar0 = br[e], ar1 = ar0, an0 = bn[e], an1 = an0;
  for (int d0 = 0; d0 < DIN; d0 += 64) {
    __syncthreads();
    for (int i = tid; i < 64 * NE / 4; i += 256) {
      int dd = i >> 4, c4 = (i & 15) * 4;
      *(float4*)&wrs[dd][c4] = *(const float4*)&Wr[(size_t)(d0 + dd) * NE + c4];
      *(float4*)&wns[dd][c4] = *(const float4*)&Wn[(size_t)(d0 + dd) * NE + c4];
    }
    __syncthreads();
    #pragma unroll 8
    for (int dd = 0; dd < 64; dd++) {
      float wr = wrs[dd][e], wn = wns[dd][e];
      float xa = xs[ta][d0 + dd], xb = xs[tb][d0 + dd];
      ar0 = fmaf(xa, wr, ar0); ar1 = fmaf(xb, wr, ar1);
      an0 = fmaf(xa, wn, an0); an1 = fmaf(xb, wn, an1);
    }
  }
  #pragma unroll
  for (int s = 0; s < 2; s++) {
    int t = t0 + ta + s;
    float lr = s ? ar1 : ar0;
    float lnv = s ? an1 : an0;
    float sp = fmaxf(lnv, 0.f) + log1pf(expf(-fabsf(lnv)));   // softplus, overflow-safe
    float v = lr + noise[(size_t)t * NE + e] * sp;
    float cur = v;
    float topv[KTOP]; int topi[KTOP];
    #pragma unroll
    for (int j = 0; j < KTOP; j++) {
      float bv = cur; int bi = e;
      #pragma unroll
      for (int off = 32; off > 0; off >>= 1) {
        float ov = __shfl_xor(bv, off);
        int   oi = __shfl_xor(bi, off);
        if (ov > bv || (ov == bv && oi < bi)) { bv = ov; bi = oi; }
      }
      topv[j] = bv; topi[j] = bi;
      if (e == bi) cur = -INFINITY;
    }
    float mx = topv[0], se = 0.f, pv[KTOP];
    #pragma unroll
    for (int j = 0; j < KTOP; j++) { pv[j] = expf(topv[j] - mx); se += pv[j]; }
    float inv = 1.f / se;
    float g = 0.f; int sl = -1;
    #pragma unroll
    for (int j = 0; j < KTOP; j++) if (topi[j] == e) { g = pv[j] * inv; sl = j; }
    gate[(size_t)t * NE + e] = (sl >= 0) ? g : 0.f;
    slotm[(size_t)t * NE + e] = sl;
  }
}

// ---------------- dispatch: stable per-expert compaction (== stable argsort) -------
__global__ __launch_bounds__(256) void dispatch_kernel(
    const float* __restrict__ gate, const int* __restrict__ slotm,
    int* __restrict__ tok_idx, float* __restrict__ tok_g,
    int* __restrict__ tok_slot, int* __restrict__ counts)
{
  const int e = blockIdx.x;
  const int tid = threadIdx.x;
  __shared__ int wave_off[4];
  int base = 0;
  for (int t0 = 0; t0 < T_TOK; t0 += 256) {
    int t = t0 + tid;
    float g = gate[(size_t)t * NE + e];
    bool p = g > 0.f;
    unsigned long long m = __ballot(p);
    int wv = tid >> 6, lane = tid & 63;
    int pre = __popcll(m & ((1ull << lane) - 1ull));
    if (lane == 0) wave_off[wv] = __popcll(m);
    __syncthreads();
    int off = 0;
    for (int w = 0; w < wv; w++) off += wave_off[w];
    int tot = wave_off[0] + wave_off[1] + wave_off[2] + wave_off[3];
    if (p) {
      int pos = base + off + pre;
      if (pos < CAPC) {
        tok_idx[(size_t)e * CAPC + pos] = t;
        tok_g[(size_t)e * CAPC + pos] = g;
        tok_slot[(size_t)e * CAPC + pos] = slotm[(size_t)t * NE + e];
      }
    }
    base += tot;
    __syncthreads();
  }
  if (tid == 0) counts[e] = min(base, CAPC);
}

// ============== GEMM with retiled bf16 B: 256x128x32, both operands gload_lds ======
// 512 thr / 8 waves; 3 LDS buffers; 3 gload_lds per thread per iter; vmcnt(3) depth-2
// pipeline, one barrier per iter. B tiles are contiguous 8KB (dense HBM stream).
template<int KD, int ND, int EPI>
__global__ __launch_bounds__(512, 2) void moe_gemm_t(
    const unsigned short* __restrict__ Abf, const unsigned short* __restrict__ Bt,
    const float* __restrict__ bias, void* __restrict__ Outp,
    const int* __restrict__ tok_idx, const float* __restrict__ tok_g,
    const int* __restrict__ tok_slot, const int* __restrict__ counts)
{
  constexpr int NK = KD / 32;
  constexpr int NP = ND / 128;
  const int e = blockIdx.z;
  const int cnt = counts[e];
  const int m0 = blockIdx.y * 256;
  if (m0 >= cnt) return;
  const int p = blockIdx.x;
  const int n0 = p * 128;
  const int tid = threadIdx.x;
  const int lane = tid & 63, wave = tid >> 6;

  __shared__ unsigned short AL[3][256][32];   // 48 KB
  __shared__ unsigned short BL[3][128][32];   // 24 KB
  __shared__ int   s_tok[EPI == 2 ? 256 : 1];
  __shared__ float s_g[EPI == 2 ? 256 : 1];
  __shared__ int   s_slot[EPI == 2 ? 256 : 1];

  if (EPI == 2 && tid < 256) {
    int gr = m0 + tid;
    if (gr < cnt) {
      s_tok[tid]  = tok_idx[(size_t)e * CAPC + gr];
      s_g[tid]    = tok_g[(size_t)e * CAPC + gr];
      s_slot[tid] = tok_slot[(size_t)e * CAPC + gr];
    }
  }

  // A staging: wave stages rows [32w,32w+32) in 2 calls; lane -> row 32w+16j+(lane>>2),
  // slot lane&3 holds global chunk ((lane&3)-((row>>1)&3))&3  (conflict-free reads)
  size_t a_src[2];
  #pragma unroll
  for (int j = 0; j < 2; j++) {
    int r = 32 * wave + 16 * j + (lane >> 2);
    int c = ((lane & 3) - ((r >> 1) & 3)) & 3;
    a_src[j] = ((size_t)e * CAPC + m0 + r) * KD + 8 * c;
  }
  const int a_dst0 = (32 * wave) * 32;
  const int a_dst1 = (32 * wave + 16) * 32;
  // B staging: wave stages 1KB of the contiguous 8KB tile
  const unsigned short* b_src = Bt + ((size_t)(e * NP + p) * NK) * 4096 + wave * 512 + lane * 8;
  const int b_dst = wave * 512;

  auto stage = [&](int t, unsigned short* Abuf, unsigned short* Bbuf) {
    glds16(Abuf + a_dst0, Abf + a_src[0] + (size_t)t * 32);
    glds16(Abuf + a_dst1, Abf + a_src[1] + (size_t)t * 32);
    glds16(Bbuf + b_dst, b_src + (size_t)t * 4096);
  };

  const int wm = 64 * (wave >> 1), wn = 64 * (wave & 1);
  const int li = lane & 15, lg = lane >> 4;
  const int kx = 8 * ((lg + ((li >> 1) & 3)) & 3);

  f32x4 acc[4][4];
  #pragma unroll
  for (int i = 0; i < 4; i++)
    #pragma unroll
    for (int j = 0; j < 4; j++) acc[i][j] = (f32x4){0.f, 0.f, 0.f, 0.f};

  auto step = [&](const unsigned short* Abuf, const unsigned short* Bbuf) {
    bf16x8 afr[4], bfr[4];
    #pragma unroll
    for (int mi = 0; mi < 4; mi++)
      afr[mi] = *(const bf16x8*)&Abuf[(wm + 16 * mi + li) * 32 + kx];
    #pragma unroll
    for (int ni = 0; ni < 4; ni++)
      bfr[ni] = *(const bf16x8*)&Bbuf[(wn + 16 * ni + li) * 32 + kx];
    __builtin_amdgcn_s_setprio(1);
    #pragma unroll
    for (int mi = 0; mi < 4; mi++)
      #pragma unroll
      for (int ni = 0; ni < 4; ni++)
        acc[mi][ni] = __builtin_amdgcn_mfma_f32_16x16x32_bf16(afr[mi], bfr[ni], acc[mi][ni], 0, 0, 0);
    __builtin_amdgcn_s_setprio(0);
  };

  unsigned short *A0 = &AL[0][0][0], *A1 = &AL[1][0][0], *A2 = &AL[2][0][0];
  unsigned short *B0 = &BL[0][0][0], *B1 = &BL[1][0][0], *B2 = &BL[2][0][0];

  stage(0, A0, B0);
  stage(1, A1, B1);
  asm volatile("s_waitcnt vmcnt(3)" ::: "memory");   // tile 0 landed
  __builtin_amdgcn_s_barrier();

  for (int kt = 0; kt < NK; kt++) {
    const int tn = (kt + 2 < NK) ? kt + 2 : NK - 1;
    stage(tn, A2, B2);              // buf (kt+2)%3: disjoint from tile kt's buf
    step(A0, B0);                   // tile kt
    asm volatile("s_waitcnt vmcnt(3)" ::: "memory");  // tile kt+1 landed
    __builtin_amdgcn_s_barrier();
    unsigned short* ta = A0; A0 = A1; A1 = A2; A2 = ta;
    unsigned short* tb = B0; B0 = B1; B1 = B2; B2 = tb;
  }
  asm volatile("s_waitcnt vmcnt(0)" ::: "memory");   // drain before WG exit

  const float* bpb = bias + (size_t)e * ND;
  #pragma unroll
  for (int mi = 0; mi < 4; mi++) {
    #pragma unroll
    for (int ni = 0; ni < 4; ni++) {
      const int ncol = n0 + wn + ni * 16 + li;
      const float bb = bpb[ncol];
      #pragma unroll
      for (int q = 0; q < 4; q++) {
        const int r = wm + mi * 16 + lg * 4 + q;
        const int gr = m0 + r;
        if (gr < cnt) {
          float v = acc[mi][ni][q] + bb;
          if (EPI == 0) {
            v = gelu_exact(v);
            ((unsigned short*)Outp)[((size_t)e * CAPC + gr) * ND + ncol] = f2bf(v);
          } else if (EPI == 1) {
            ((unsigned short*)Outp)[((size_t)e * CAPC + gr) * ND + ncol] = f2bf(v);
          } else {
            ((float*)Outp)[((size_t)s_tok[r] * KTOP + s_slot[r]) * OD + ncol] = v * s_g[r];
          }
        }
      }
    }
  }
}

// ============== BIG expert GEMM (r5): 256x128x32 fp32-B, used for GEMM1 + fallback ==
template<int KD, int NDT, bool AGATHER, int EPI>
__global__ __launch_bounds__(512, 1) void moe_gemm_big(
    const unsigned short* __restrict__ Abf, const float* __restrict__ Bw,
    const float* __restrict__ bias, void* __restrict__ Outp,
    const int* __restrict__ tok_idx, const float* __restrict__ tok_g,
    const int* __restrict__ tok_slot, const int* __restrict__ counts)
{
  constexpr int NK = KD / 32;
  static_assert(NK % 4 == 0 && NK >= 8, "NK must be multiple of 4");
  const int e = blockIdx.z;
  const int cnt = counts[e];
  const int m0 = blockIdx.y * 256;
  if (m0 >= cnt) return;
  const int n0 = blockIdx.x * 128;
  const int tid = threadIdx.x;
  const int lane = tid & 63, wave = tid >> 6;

  __shared__ unsigned short AL[4][256][32];
  __shared__ unsigned short BL[4][128][40];
  __shared__ int   s_tok[256];
  __shared__ float s_g[256];
  __shared__ int   s_slot[256];

  if (EPI == 2 && tid < 256) {
    int gr = m0 + tid;
    if (gr < cnt) {
      s_tok[tid]  = tok_idx[(size_t)e * CAPC + gr];
      s_g[tid]    = tok_g[(size_t)e * CAPC + gr];
      s_slot[tid] = tok_slot[(size_t)e * CAPC + gr];
    }
  }

  const bool isB = wave < 4;
  const int  w4  = wave & 3;

  const float* bp = Bw + (size_t)e * KD * NDT + (size_t)(8 * w4) * NDT + n0 + 2 * lane;
  float2 breg[4][8];

  size_t a_off[4];
  if (!isB) {
    #pragma unroll
    for (int q = 0; q < 4; q++) {
      int r  = w4 * 64 + q * 16 + (lane >> 2);
      int cq = ((lane & 3) - (r >> 1)) & 3;
      size_t rowb;
      if (AGATHER) {
        int gr = m0 + r;
        int tk = (gr < cnt) ? tok_idx[(size_t)e * CAPC + gr] : 0;
        rowb = (size_t)tk * KD;
      } else {
        rowb = ((size_t)e * CAPC + m0 + r) * KD;
      }
      a_off[q] = rowb + 8 * cq;
    }
  }

  auto stageA = [&](int t, int s) {
    #pragma unroll
    for (int q = 0; q < 4; q++)
      glds16(&AL[s][0][0] + w4 * 2048 + q * 512, Abf + a_off[q] + (size_t)t * 32);
  };
  auto loadB = [&](int t, int p) {
    const float* pb = bp + (size_t)t * 32 * NDT;
    #pragma unroll
    for (int j = 0; j < 8; j++) breg[p][j] = *(const float2*)(pb + (size_t)j * NDT);
  };
  auto writeB = [&](int s, int p) {
    uint4 rx, ry;
    rx.x = cvt2(breg[p][0].x, breg[p][1].x); rx.y = cvt2(breg[p][2].x, breg[p][3].x);
    rx.z = cvt2(breg[p][4].x, breg[p][5].x); rx.w = cvt2(breg[p][6].x, breg[p][7].x);
    ry.x = cvt2(breg[p][0].y, breg[p][1].y); ry.y = cvt2(breg[p][2].y, breg[p][3].y);
    ry.z = cvt2(breg[p][4].y, breg[p][5].y); ry.w = cvt2(breg[p][6].y, breg[p][7].y);
    *(uint4*)&BL[s][2 * lane][8 * w4]     = rx;
    *(uint4*)&BL[s][2 * lane + 1][8 * w4] = ry;
  };

  const int wm = (wave >> 1) * 64;
  const int wn = (wave & 1) * 64;
  const int li = lane & 15, lg = lane >> 4;
  const int kxa = 8 * ((lg + ((li >> 1) & 3)) & 3);

  f32x4 acc[4][4];
  #pragma unroll
  for (int i = 0; i < 4; i++)
    #pragma unroll
    for (int j = 0; j < 4; j++) acc[i][j] = (f32x4){0.f, 0.f, 0.f, 0.f};

  auto step = [&](int s) {
    bf16x8 afr[4], bfr[4];
    #pragma unroll
    for (int mi = 0; mi < 4; mi++)
      afr[mi] = *(const bf16x8*)&AL[s][wm + mi * 16 + li][kxa];
    #pragma unroll
    for (int ni = 0; ni < 4; ni++)
      bfr[ni] = *(const bf16x8*)&BL[s][wn + ni * 16 + li][lg * 8];
    __builtin_amdgcn_s_setprio(1);
    #pragma unroll
    for (int mi = 0; mi < 4; mi++)
      #pragma unroll
      for (int ni = 0; ni < 4; ni++)
        acc[mi][ni] = __builtin_amdgcn_mfma_f32_16x16x32_bf16(afr[mi], bfr[ni], acc[mi][ni], 0, 0, 0);
    __builtin_amdgcn_s_setprio(0);
  };

  if (isB) {
    loadB(0, 0); loadB(1, 1); loadB(2, 2);
    asm volatile("s_waitcnt vmcnt(16)" ::: "memory");
    writeB(0, 0);
    asm volatile("s_waitcnt lgkmcnt(0)" ::: "memory");
  } else {
    stageA(0, 0); stageA(1, 1); stageA(2, 2);
    asm volatile("s_waitcnt vmcnt(8)" ::: "memory");
  }
  __builtin_amdgcn_s_barrier();

  #define SUBITER(p)                                                        \
    do {                                                                    \
      const int jj = jb + (p);                                              \
      if (isB) loadB(min(jj + 3, NK - 1), ((p) + 3) & 3);                   \
      else     stageA(min(jj + 3, NK - 1), ((p) + 3) & 3);                  \
      step(p);                                                              \
      if (isB) {                                                            \
        asm volatile("s_waitcnt vmcnt(16)" ::: "memory");                   \
        writeB(((p) + 1) & 3, ((p) + 1) & 3);                               \
        asm volatile("s_waitcnt lgkmcnt(0)" ::: "memory");                  \
      } else {                                                              \
        asm volatile("s_waitcnt vmcnt(8)" ::: "memory");                    \
      }                                                                     \
      __builtin_amdgcn_s_barrier();                                         \
    } while (0)

  for (int jb = 0; jb < NK; jb += 4) {
    SUBITER(0); SUBITER(1); SUBITER(2); SUBITER(3);
  }
  #undef SUBITER
  asm volatile("s_waitcnt vmcnt(0)" ::: "memory");

  const float* bpb = bias + (size_t)e * NDT;
  #pragma unroll
  for (int mi = 0; mi < 4; mi++) {
    #pragma unroll
    for (int ni = 0; ni < 4; ni++) {
      const int ncol = n0 + wn + ni * 16 + li;
      const float bb = bpb[ncol];
      #pragma unroll
      for (int q = 0; q < 4; q++) {
        const int r = wm + mi * 16 + lg * 4 + q;
        const int gr = m0 + r;
        if (gr < cnt) {
          float v = acc[mi][ni][q] + bb;
          if (EPI == 0) {
            v = gelu_exact(v);
            ((unsigned short*)Outp)[((size_t)e * CAPC + gr) * NDT + ncol] = f2bf(v);
          } else if (EPI == 1) {
            ((unsigned short*)Outp)[((size_t)e * CAPC + gr) * NDT + ncol] = f2bf(v);
          } else {
            ((float*)Outp)[((size_t)s_tok[r] * KTOP + s_slot[r]) * OD + ncol] = v * s_g[r];
          }
        }
      }
    }
  }
}

// ---------------- 128x128x32 expert GEMM (r4) for fallback G3/G4 -------------------
template<int KD, int ND, bool AGATHER, int EPI>
__global__ __launch_bounds__(256, 2) void moe_gemm(
    const unsigned short* __restrict__ Abf, const float* __restrict__ Bw,
    const float* __restrict__ bias, void* __restrict__ Outp,
    const int* __restrict__ tok_idx, const float* __restrict__ tok_g,
    const int* __restrict__ tok_slot, const int* __restrict__ counts)
{
  constexpr int NK = KD / 32;
  static_assert(NK % 4 == 0 && NK >= 8, "NK must be multiple of 4");
  const int e = blockIdx.z;
  const int cnt = counts[e];
  const int m0 = blockIdx.y * 128;
  if (m0 >= cnt) return;
  const int n0 = blockIdx.x * 128;
  const int tid = threadIdx.x;

  __shared__ unsigned short AL[4][128][32];
  __shared__ unsigned short BL[4][128][40];
  __shared__ int   s_tok[128];
  __shared__ float s_g[128];
  __shared__ int   s_slot[128];

  if (EPI == 2 && tid < 128) {
    int gr = m0 + tid;
    if (gr < cnt) {
      s_tok[tid]  = tok_idx[(size_t)e * CAPC + gr];
      s_g[tid]    = tok_g[(size_t)e * CAPC + gr];
      s_slot[tid] = tok_slot[(size_t)e * CAPC + gr];
    }
  }

  const int ar0 = tid >> 2;
  const int ac  = 8 * (((tid & 3) - (tid >> 3)) & 3);
  size_t arow0, arow1;
  if (AGATHER) {
    int g0 = m0 + ar0, g1 = m0 + 64 + ar0;
    int t0i = (g0 < cnt) ? tok_idx[(size_t)e * CAPC + g0] : 0;
    int t1i = (g1 < cnt) ? tok_idx[(size_t)e * CAPC + g1] : 0;
    arow0 = (size_t)t0i * KD; arow1 = (size_t)t1i * KD;
  } else {
    arow0 = ((size_t)e * CAPC + m0 + ar0) * KD;
    arow1 = arow0 + (size_t)64 * KD;
  }
  const unsigned short* ap0 = Abf + arow0 + ac;
  const unsigned short* ap1 = Abf + arow1 + ac;
  const int awb = (tid & 192) * 8;

  const int l = tid & 63, w = tid >> 6;
  const float* bp = Bw + (size_t)e * KD * ND + (size_t)(8 * w) * ND + n0 + 2 * l;

  float2 breg[4][8];

  auto stageA = [&](int t, int s) {
    glds16(&AL[s][0][0] + awb,        ap0 + t * 32);
    glds16(&AL[s][0][0] + 2048 + awb, ap1 + t * 32);
  };
  auto loadB = [&](int t, int p) {
    const float* pb = bp + (size_t)t * 32 * ND;
    #pragma unroll
    for (int j = 0; j < 8; j++) breg[p][j] = *(const float2*)(pb + (size_t)j * ND);
  };
  auto writeB = [&](int s, int p) {
    uint4 rx, ry;
    rx.x = cvt2(breg[p][0].x, breg[p][1].x); rx.y = cvt2(breg[p][2].x, breg[p][3].x);
    rx.z = cvt2(breg[p][4].x, breg[p][5].x); rx.w = cvt2(breg[p][6].x, breg[p][7].x);
    ry.x = cvt2(breg[p][0].y, breg[p][1].y); ry.y = cvt2(breg[p][2].y, breg[p][3].y);
    ry.z = cvt2(breg[p][4].y, breg[p][5].y); ry.w = cvt2(breg[p][6].y, breg[p][7].y);
    *(uint4*)&BL[s][2 * l][8 * w]     = rx;
    *(uint4*)&BL[s][2 * l + 1][8 * w] = ry;
  };

  const int lane = tid & 63, wv = tid >> 6;
  const int wm = (wv >> 1) * 64, wn = (wv & 1) * 64;
  const int li = lane & 15, lg = lane >> 4;
  const int kxa = 8 * ((lg + ((li >> 1) & 3)) & 3);

  f32x4 acc[4][4];
  #pragma unroll
  for (int i = 0; i < 4; i++)
    #pragma unroll
    for (int j = 0; j < 4; j++) acc[i][j] = (f32x4){0.f, 0.f, 0.f, 0.f};

  auto step = [&](int s) {
    bf16x8 afr[4], bfr[4];
    #pragma unroll
    for (int mi = 0; mi < 4; mi++)
      afr[mi] = *(const bf16x8*)&AL[s][wm + mi * 16 + li][kxa];
    #pragma unroll
    for (int ni = 0; ni < 4; ni++)
      bfr[ni] = *(const bf16x8*)&BL[s][wn + ni * 16 + li][lg * 8];
    __builtin_amdgcn_s_setprio(1);
    #pragma unroll
    for (int mi = 0; mi < 4; mi++)
      #pragma unroll
      for (int ni = 0; ni < 4; ni++)
        acc[mi][ni] = __builtin_amdgcn_mfma_f32_16x16x32_bf16(afr[mi], bfr[ni], acc[mi][ni], 0, 0, 0);
    __builtin_amdgcn_s_setprio(0);
  };

  loadB(0, 0);
  stageA(0, 0); loadB(1, 1);
  stageA(1, 1); loadB(2, 2);
  stageA(2, 2); loadB(3, 3);
  asm volatile("s_waitcnt vmcnt(28)" ::: "memory");
  writeB(0, 0);
  asm volatile("s_waitcnt lgkmcnt(0)" ::: "memory");
  __builtin_amdgcn_s_barrier();

  #define SUBITER(p)                                                        \
    do {                                                                    \
      const int jj = jb + (p);                                              \
      stageA(min(jj + 3, NK - 1), ((p) + 3) & 3);                           \
      loadB(min(jj + 4, NK - 1), (p));                                      \
      step(p);                                                              \
      asm volatile("s_waitcnt vmcnt(28)" ::: "memory");                     \
      writeB(((p) + 1) & 3, ((p) + 1) & 3);                                 \
      asm volatile("s_waitcnt lgkmcnt(0)" ::: "memory");                    \
      __builtin_amdgcn_s_barrier();                                         \
    } while (0)

  for (int jb = 0; jb < NK; jb += 4) {
    SUBITER(0); SUBITER(1); SUBITER(2); SUBITER(3);
  }
  #undef SUBITER
  asm volatile("s_waitcnt vmcnt(0)" ::: "memory");

  const float* bpb = bias + (size_t)e * ND;
  #pragma unroll
  for (int mi = 0; mi < 4; mi++) {
    #pragma unroll
    for (int ni = 0; ni < 4; ni++) {
      const int ncol = n0 + wn + ni * 16 + li;
      const float bb = bpb[ncol];
      #pragma unroll
      for (int q = 0; q < 4; q++) {
        const int r = wm + mi * 16 + lg * 4 + q;
        const int gr = m0 + r;
        if (gr < cnt) {
          float v = acc[mi][ni][q] + bb;
          if (EPI == 0) {
            v = gelu_exact(v);
            ((unsigned short*)Outp)[((size_t)e * CAPC + gr) * ND + ncol] = f2bf(v);
          } else if (EPI == 1) {
            ((unsigned short*)Outp)[((size_t)e * CAPC + gr) * ND + ncol] = f2bf(v);
          } else {
            ((float*)Outp)[((size_t)s_tok[r] * KTOP + s_slot[r]) * OD + ncol] = v * s_g[r];
          }
        }
      }
    }
  }
}

// ---------------- combine 8 slots + LayerNorm -------------------------------------
__global__ __launch_bounds__(256) void combine_ln(
    const float* __restrict__ yd, const float* __restrict__ lw,
    const float* __restrict__ lb, float* __restrict__ out)
{
  const int t = blockIdx.x, tid = threadIdx.x;
  float v[3];
  #pragma unroll
  for (int i = 0; i < 3; i++) {
    const int c = tid + 256 * i;
    float s = 0.f;
    #pragma unroll
    for (int j = 0; j < KTOP; j++) s += yd[((size_t)t * KTOP + j) * OD + c];
    v[i] = s;
  }
  float s1 = v[0] + v[1] + v[2];
  float s2 = v[0] * v[0] + v[1] * v[1] + v[2] * v[2];
  #pragma unroll
  for (int off = 32; off > 0; off >>= 1) {
    s1 += __shfl_xor(s1, off);
    s2 += __shfl_xor(s2, off);
  }
  __shared__ float as1[4], as2[4];
  const int lane = tid & 63, wv = tid >> 6;
  if (lane == 0) { as1[wv] = s1; as2[wv] = s2; }
  __syncthreads();
  s1 = as1[0] + as1[1] + as1[2] + as1[3];
  s2 = as2[0] + as2[1] + as2[2] + as2[3];
  const float mu = s1 * (1.f / OD);
  const float var = s2 * (1.f / OD) - mu * mu;
  const float rstd = rsqrtf(var + 1e-5f);
  #pragma unroll
  for (int i = 0; i < 3; i++) {
    const int c = tid + 256 * i;
    out[(size_t)t * OD + c] = (v[i] - mu) * rstd * lw[c] + lb[c];
  }
}

extern "C" void kernel_launch(void* const* d_in, const int* in_sizes, int n_in,
                              void* d_out, int out_size, void* d_ws, size_t ws_size,
                              hipStream_t stream) {
  const float* x     = (const float*)d_in[0];
  const float* noise = (const float*)d_in[1];
  const float* Wr    = (const float*)d_in[2];
  const float* br    = (const float*)d_in[3];
  const float* Wn    = (const float*)d_in[4];
  const float* bn    = (const float*)d_in[5];
  const float* W1    = (const float*)d_in[6];
  const float* b1    = (const float*)d_in[7];
  const float* W2    = (const float*)d_in[8];
  const float* b2    = (const float*)d_in[9];
  const float* W3    = (const float*)d_in[10];
  const float* b3    = (const float*)d_in[11];
  const float* Wo    = (const float*)d_in[12];
  const float* bo    = (const float*)d_in[13];
  const float* lw    = (const float*)d_in[14];
  const float* lb    = (const float*)d_in[15];
  float* out = (float*)d_out;

  char* ws = (char*)d_ws;
  constexpr size_t OFF_GATE = 0;
  constexpr size_t OFF_SLOT = OFF_GATE + (size_t)T_TOK * NE * 4;
  constexpr size_t OFF_TIDX = OFF_SLOT + (size_t)T_TOK * NE * 4;
  constexpr size_t OFF_TG   = OFF_TIDX + (size_t)NE * CAPC * 4;
  constexpr size_t OFF_TSL  = OFF_TG + (size_t)NE * CAPC * 4;
  constexpr size_t OFF_CNT  = OFF_TSL + (size_t)NE * CAPC * 4;
  constexpr size_t OFF_YD   = ((OFF_CNT + NE * 4) + 255) & ~(size_t)255;
  constexpr size_t SZ_YD    = (size_t)T_TOK * KTOP * OD * 4;
  constexpr size_t OFF_H1   = OFF_YD + SZ_YD;
  constexpr size_t OFF_H2   = OFF_H1 + (size_t)NE * CAPC * HD * 2;
  constexpr size_t OFF_H3   = OFF_H2 + (size_t)NE * CAPC * HD * 2;
  constexpr size_t OFF_XBF  = OFF_H3 + (size_t)NE * CAPC * BTD * 2;
  constexpr size_t OFF_W2T  = ((OFF_XBF + (size_t)T_TOK * DIN * 2) + 255) & ~(size_t)255;
  constexpr size_t SZ_W2T   = (size_t)NE * (HD / 128) * (HD / 32) * 4096 * 2;   // 537 MB
  constexpr size_t OFF_W3T  = OFF_W2T + SZ_W2T;
  constexpr size_t SZ_W3T   = (size_t)NE * (BTD / 128) * (HD / 32) * 4096 * 2;  // 67 MB
  constexpr size_t OFF_WOT  = OFF_W3T + SZ_W3T;
  constexpr size_t SZ_WOT   = (size_t)NE * (OD / 128) * (BTD / 32) * 4096 * 2;  // 25 MB
  constexpr size_t NEED     = OFF_WOT + SZ_WOT;

  float* gate = (float*)(ws + OFF_GATE);
  int*   slot = (int*)(ws + OFF_SLOT);
  int*   tidx = (int*)(ws + OFF_TIDX);
  float* tg   = (float*)(ws + OFF_TG);
  int*   tsl  = (int*)(ws + OFF_TSL);
  int*   cnts = (int*)(ws + OFF_CNT);
  float* yd   = (float*)(ws + OFF_YD);
  unsigned short* h1  = (unsigned short*)(ws + OFF_H1);
  unsigned short* h2  = (unsigned short*)(ws + OFF_H2);
  unsigned short* h3  = (unsigned short*)(ws + OFF_H3);
  unsigned short* xbf = (unsigned short*)(ws + OFF_XBF);
  unsigned short* w2t = (unsigned short*)(ws + OFF_W2T);
  unsigned short* w3t = (unsigned short*)(ws + OFF_W3T);
  unsigned short* wot = (unsigned short*)(ws + OFF_WOT);

  hipMemsetAsync(yd, 0, SZ_YD, stream);
  cvt_x<<<T_TOK * DIN / 4 / 256, 256, 0, stream>>>(x, xbf);

  if (ws_size >= NEED) {
    // dense-retile path
    retile_w<HD, HD><<<dim3(HD / 32, NE), 256, 0, stream>>>(W2, w2t);
    retile_w<HD, BTD><<<dim3(HD / 32, NE), 256, 0, stream>>>(W3, w3t);
    retile_w<BTD, OD><<<dim3(BTD / 32, NE), 256, 0, stream>>>(Wo, wot);
    router_kernel<<<T_TOK / 8, 256, 0, stream>>>(x, noise, Wr, br, Wn, bn, gate, slot);
    dispatch_kernel<<<NE, 256, 0, stream>>>(gate, slot, tidx, tg, tsl, cnts);
    moe_gemm_big<DIN, HD, true, 0><<<dim3(HD / 128, CAPC / 256, NE), 512, 0, stream>>>(
        xbf, W1, b1, h1, tidx, tg, tsl, cnts);
    moe_gemm_t<HD, HD, 0><<<dim3(HD / 128, CAPC / 256, NE), 512, 0, stream>>>(
        h1, w2t, b2, h2, tidx, tg, tsl, cnts);
    moe_gemm_t<HD, BTD, 1><<<dim3(BTD / 128, CAPC / 256, NE), 512, 0, stream>>>(
        h2, w3t, b3, h3, tidx, tg, tsl, cnts);
    moe_gemm_t<BTD, OD, 2><<<dim3(OD / 128, CAPC / 256, NE), 512, 0, stream>>>(
        h3, wot, bo, yd, tidx, tg, tsl, cnts);
  } else {
    // fallback: r5 path (no extra workspace needed)
    router_kernel<<<T_TOK / 8, 256, 0, stream>>>(x, noise, Wr, br, Wn, bn, gate, slot);
    dispatch_kernel<<<NE, 256, 0, stream>>>(gate, slot, tidx, tg, tsl, cnts);
    moe_gemm_big<DIN, HD, true, 0><<<dim3(HD / 128, CAPC / 256, NE), 512, 0, stream>>>(
        xbf, W1, b1, h1, tidx, tg, tsl, cnts);
    moe_gemm_big<HD, HD, false, 0><<<dim3(HD / 128, CAPC / 256, NE), 512, 0, stream>>>(
        h1, W2, b2, h2, tidx, tg, tsl, cnts);
    moe_gemm<HD, BTD, false, 1><<<dim3(BTD / 128, CAPC / 128, NE), 256, 0, stream>>>(
        h2, W3, b3, h3, tidx, tg, tsl, cnts);
    moe_gemm<BTD, OD, false, 2><<<dim3(OD / 128, CAPC / 128, NE), 256, 0, stream>>>(
        h3, Wo, bo, yd, tidx, tg, tsl, cnts);
  }
  combine_ln<<<T_TOK, 256, 0, stream>>>(yd, lw, lb, out);
}